// Round 5
// baseline (103.484 us; speedup 1.0000x reference)
//
#include <hip/hip_runtime.h>
#include <hip/hip_bf16.h>
#include <math.h>

#define NF 64
#define NC 16
#define MAIN_BLOCKS 256
#define MAIN_WAVES  8                  // waves per main block
#define TPW 7                          // 16-sample subtiles per wave (112 samples)

typedef __bf16 bf16x8 __attribute__((ext_vector_type(8)));
typedef float f32x4 __attribute__((ext_vector_type(4)));
typedef unsigned int u32;

// async global->LDS, 16B/lane. LDS dest = wave-uniform base (HW adds lane*16).
__device__ __forceinline__ void stage16(const void* gsrc, void* ldst) {
    __builtin_amdgcn_global_load_lds(
        (const __attribute__((address_space(1))) u32*)gsrc,
        (__attribute__((address_space(3))) u32*)ldst,
        16, 0, 0);
}

// ---------------------------------------------------------------------------
// Kernel 1 v5: 4 blocks x 256 threads; one component per WAVE (k = bid*4+w).
// 4 waves/CU share the straight-line I-stream -> I-cache misses amortized.
// Rank-1 register Cholesky with lookahead-pipelined LDS broadcast:
//   step j's pivot row was written EARLY in step j-1 (before the tail FMAs),
//   so the 120-cyc LDS write->read latency hides under the update tail.
// Substitution: readlane chain on register row l[] (no LDS).
// No __syncthreads anywhere: waves are independent; within-wave LDS is
// in-order (compiler inserts lgkmcnt for may-alias accesses).
// ---------------------------------------------------------------------------
__global__ __launch_bounds__(256, 1) void gmm_precompute(
    const float* __restrict__ cov,
    const float* __restrict__ means,
    const float* __restrict__ weights,
    __hip_bfloat16* __restrict__ g,
    float* __restrict__ t,
    float* __restrict__ Cc)
{
    const int w = threadIdx.x >> 6;
    const int c = threadIdx.x & 63;        // lane owns column c
    const int k = blockIdx.x * 4 + w;      // component

    __shared__ float Xs[4][NF][NF + 1];            // per-wave transpose buffer
    __shared__ __align__(16) float wbuf[4][2][68]; // per-wave ping-pong row bcast

    float* wb0 = &wbuf[w][0][0];
    float* wb1 = &wbuf[w][1][0];

    // column c of cov (addresses lane-consecutive per i -> coalesced)
    float a[NF];
    {
        const float* src = cov + (long)k * NF * NF + c;
        #pragma unroll
        for (int i = 0; i < NF; ++i)
            a[i] = src[i * NF];
    }

    wb0[c] = a[0];                 // row 0 == col 0 by symmetry

    float l[NF];
    float logdiag = 0.0f;

    #pragma unroll
    for (int j = 0; j < NF; ++j) {
        float* cur = (j & 1) ? wb1 : wb0;
        float* nxt = (j & 1) ? wb0 : wb1;
        float d   = cur[j];                  // broadcast pivot (written step j-1)
        float sq  = sqrtf(d);
        float rd  = 1.0f / d;
        logdiag  += __logf(sq);              // uniform across lanes
        float beta = a[j] * rd;
        l[j] = beta * sq;                    // = a[j]/sqrt(d) = L[c][j]
        if (j + 1 < NF) {
            // lookahead: finalize next pivot row element first, publish it
            a[j + 1] = fmaf(-cur[j + 1], beta, a[j + 1]);
            nxt[c] = a[j + 1];
            // tail updates (independent FMAs), float4 broadcast reads
            #pragma unroll
            for (int i = j + 2; i < ((j + 5) & ~3) && i < NF; ++i)
                a[i] = fmaf(-cur[i], beta, a[i]);
            #pragma unroll
            for (int i = (j + 5) & ~3; i < NF; i += 4) {
                float4 v = *(const float4*)(cur + i);
                a[i]     = fmaf(-v.x, beta, a[i]);
                a[i + 1] = fmaf(-v.y, beta, a[i + 1]);
                a[i + 2] = fmaf(-v.z, beta, a[i + 2]);
                a[i + 3] = fmaf(-v.w, beta, a[i + 3]);
            }
        }
    }

    // forward substitution: lane c = column c of G = L^{-1}; L[i][p] via readlane
    float x[NF];
    #pragma unroll
    for (int i = 0; i < NF; ++i) {
        float s0 = (i == c) ? 1.0f : 0.0f;
        float s1 = 0.0f;
        #pragma unroll
        for (int p = 0; p + 1 < i; p += 2) {
            s0 = fmaf(-__shfl(l[p],     i), x[p],     s0);
            s1 = fmaf(-__shfl(l[p + 1], i), x[p + 1], s1);
        }
        if (i & 1)
            s0 = fmaf(-__shfl(l[i - 1], i), x[i - 1], s0);
        float rdi = 1.0f / __shfl(l[i], i);
        x[i] = (i >= c) ? (s0 + s1) * rdi : 0.0f;
    }

    // transpose through per-wave LDS (single wave: in-order, no barrier)
    #pragma unroll
    for (int i = 0; i < NF; ++i) Xs[w][i][c] = x[i];

    // g row c, bf16x8 chunks at XOR-swizzled chunk positions (jb ^ (row&7))
    {
        __hip_bfloat16* grow = g + ((long)(k * NF + c)) * NF;
        #pragma unroll
        for (int jb = 0; jb < 8; ++jb) {
            bf16x8 v;
            #pragma unroll
            for (int u = 0; u < 8; ++u)
                v[u] = (__bf16)Xs[w][c][jb * 8 + u];
            *(bf16x8*)(grow + ((jb ^ (c & 7)) * 8)) = v;
        }
    }

    // t[c] = dot(G row c, mu)
    {
        const float* mu = means + k * NF;
        float a0 = 0.0f, a1 = 0.0f;
        #pragma unroll
        for (int j = 0; j < NF; j += 2) {
            a0 = fmaf(Xs[w][c][j],     mu[j],     a0);
            a1 = fmaf(Xs[w][c][j + 1], mu[j + 1], a1);
        }
        t[k * NF + c] = a0 + a1;
    }

    if (c == 0)
        Cc[k] = __logf(weights[k]) - 0.5f * (float)NF * 1.8378770664093453f - logdiag;
}

// ---------------------------------------------------------------------------
// Kernel 2 v5: persistent G-in-LDS. 256 blocks x 512 threads (8 waves).
// Stage ALL 16 components (128 KiB, pre-swizzled) once; ONE barrier; then
// each wave processes its 112-sample tile with zero barriers:
//   16 components x { 8 ds_read_b128 (swizzled), 4 t-loads, 56 MFMA,
//                     squares, online logsumexp }.
// t/Cc read from global (L1/L2-hot, 4KB) to keep LDS at exactly 128 KiB.
// ---------------------------------------------------------------------------
__global__ __launch_bounds__(512, 2) void gmm_main(
    const float* __restrict__ data,
    const char* __restrict__ gsw,         // swizzled bf16 G, [NC][8192 B]
    const float* __restrict__ t,
    const float* __restrict__ Cc,
    float* __restrict__ partials,
    int nTiles, int N, int totalWaves)
{
    __shared__ __align__(16) char gbuf[NC * 8192];   // exactly 128 KiB

    const int tidx = threadIdx.x;
    const int w    = tidx >> 6;
    const int lane = tidx & 63;
    const int l15  = lane & 15;
    const int lg   = lane >> 4;

    // stage all of G: per comp, wave w covers bytes [w*1024, w*1024+1024)
    #pragma unroll
    for (int i = 0; i < NC; ++i) {
        int off = i * 8192 + w * 1024;
        stage16(gsw + off + lane * 16, gbuf + off);
    }

    const int gid = blockIdx.x * MAIN_WAVES + w;

    // swizzled LDS byte offsets (static per lane)
    int offA[4], offB[4];
    #pragma unroll
    for (int rc = 0; rc < 4; ++rc) {
        int row = rc * 16 + l15;
        offA[rc] = row * 128 + ((lg       ^ (l15 & 7)) * 16);
        offB[rc] = row * 128 + (((lg + 4) ^ (l15 & 7)) * 16);
    }

    // prefetch first tile's x fragments (overlaps the G staging flight)
    bf16x8 xf[TPW][2];
    if (gid < nTiles) {
        const long base = (long)gid * (TPW * 16);
        #pragma unroll
        for (int st = 0; st < TPW; ++st) {
            long row = base + st * 16 + l15;
            if (row > (long)N - 1) row = (long)N - 1;
            const float* xp = data + row * NF + lg * 8;
            float4 a0 = *(const float4*)(xp);
            float4 a1 = *(const float4*)(xp + 4);
            float4 b0 = *(const float4*)(xp + 32);
            float4 b1 = *(const float4*)(xp + 36);
            bf16x8 f0, f1;
            f0[0] = (__bf16)a0.x; f0[1] = (__bf16)a0.y;
            f0[2] = (__bf16)a0.z; f0[3] = (__bf16)a0.w;
            f0[4] = (__bf16)a1.x; f0[5] = (__bf16)a1.y;
            f0[6] = (__bf16)a1.z; f0[7] = (__bf16)a1.w;
            f1[0] = (__bf16)b0.x; f1[1] = (__bf16)b0.y;
            f1[2] = (__bf16)b0.z; f1[3] = (__bf16)b0.w;
            f1[4] = (__bf16)b1.x; f1[5] = (__bf16)b1.y;
            f1[6] = (__bf16)b1.z; f1[7] = (__bf16)b1.w;
            xf[st][0] = f0;
            xf[st][1] = f1;
        }
    }

    __syncthreads();   // G staged; only barrier in the kernel

    float wavePartial = 0.0f;

    #pragma unroll 1
    for (int tile = gid; tile < nTiles; tile += totalWaves) {
        const long base = (long)tile * (TPW * 16);
        if (tile != gid) {     // grid-stride continuation (rare)
            #pragma unroll
            for (int st = 0; st < TPW; ++st) {
                long row = base + st * 16 + l15;
                if (row > (long)N - 1) row = (long)N - 1;
                const float* xp = data + row * NF + lg * 8;
                float4 a0 = *(const float4*)(xp);
                float4 a1 = *(const float4*)(xp + 4);
                float4 b0 = *(const float4*)(xp + 32);
                float4 b1 = *(const float4*)(xp + 36);
                bf16x8 f0, f1;
                f0[0] = (__bf16)a0.x; f0[1] = (__bf16)a0.y;
                f0[2] = (__bf16)a0.z; f0[3] = (__bf16)a0.w;
                f0[4] = (__bf16)a1.x; f0[5] = (__bf16)a1.y;
                f0[6] = (__bf16)a1.z; f0[7] = (__bf16)a1.w;
                f1[0] = (__bf16)b0.x; f1[1] = (__bf16)b0.y;
                f1[2] = (__bf16)b0.z; f1[3] = (__bf16)b0.w;
                f1[4] = (__bf16)b1.x; f1[5] = (__bf16)b1.y;
                f1[6] = (__bf16)b1.z; f1[7] = (__bf16)b1.w;
                xf[st][0] = f0;
                xf[st][1] = f1;
            }
        }

        float m[TPW], s[TPW];
        #pragma unroll
        for (int st = 0; st < TPW; ++st) { m[st] = -INFINITY; s[st] = 0.0f; }

        #pragma unroll 2
        for (int k = 0; k < NC; ++k) {
            float mah[TPW];
            #pragma unroll
            for (int st = 0; st < TPW; ++st) mah[st] = 0.0f;

            #pragma unroll
            for (int rc = 0; rc < 4; ++rc) {
                bf16x8 ga = *(const bf16x8*)(gbuf + k * 8192 + offA[rc]);
                bf16x8 gb = *(const bf16x8*)(gbuf + k * 8192 + offB[rc]);
                f32x4 tv  = *(const f32x4*)(t + k * NF + rc * 16 + lg * 4);
                f32x4 ntv;
                ntv[0] = -tv[0]; ntv[1] = -tv[1];
                ntv[2] = -tv[2]; ntv[3] = -tv[3];
                #pragma unroll
                for (int st = 0; st < TPW; ++st) {
                    f32x4 acc = ntv;
                    acc = __builtin_amdgcn_mfma_f32_16x16x32_bf16(ga, xf[st][0], acc, 0, 0, 0);
                    acc = __builtin_amdgcn_mfma_f32_16x16x32_bf16(gb, xf[st][1], acc, 0, 0, 0);
                    mah[st] = fmaf(acc[0], acc[0], mah[st]);
                    mah[st] = fmaf(acc[1], acc[1], mah[st]);
                    mah[st] = fmaf(acc[2], acc[2], mah[st]);
                    mah[st] = fmaf(acc[3], acc[3], mah[st]);
                }
            }

            float Ck = Cc[k];
            #pragma unroll
            for (int st = 0; st < TPW; ++st) {
                float v = mah[st];
                v += __shfl_xor(v, 16);
                v += __shfl_xor(v, 32);      // all lanes hold full maha
                float wlp = fmaf(-0.5f, v, Ck);
                float mo = m[st];
                float mn = fmaxf(mo, wlp);
                s[st] = s[st] * __expf(mo - mn) + __expf(wlp - mn);
                m[st] = mn;
            }
        }

        if (lg == 0) {
            #pragma unroll
            for (int st = 0; st < TPW; ++st) {
                long sid = base + st * 16 + l15;
                if (sid < (long)N)
                    wavePartial += m[st] + __logf(s[st]);
            }
        }
    }

    // wave reduce + per-wave slot (deterministic)
    #pragma unroll
    for (int off = 1; off < 64; off <<= 1)
        wavePartial += __shfl_xor(wavePartial, off);
    if (lane == 0)
        partials[gid] = wavePartial;
}

// ---------------------------------------------------------------------------
// Kernel 3: deterministic final reduction over per-wave partials.
// ---------------------------------------------------------------------------
__global__ __launch_bounds__(256) void gmm_reduce(
    const float* __restrict__ partials, int n, float* __restrict__ out)
{
    float s = 0.0f;
    for (int i = threadIdx.x; i < n; i += 256)
        s += partials[i];
    #pragma unroll
    for (int off = 1; off < 64; off <<= 1)
        s += __shfl_xor(s, off);
    __shared__ float sm[4];
    const int wave = threadIdx.x >> 6;
    const int lane = threadIdx.x & 63;
    if (lane == 0) sm[wave] = s;
    __syncthreads();
    if (threadIdx.x == 0)
        out[0] = (sm[0] + sm[1]) + (sm[2] + sm[3]);
}

// ---------------------------------------------------------------------------
extern "C" void kernel_launch(void* const* d_in, const int* in_sizes, int n_in,
                              void* d_out, int out_size, void* d_ws, size_t ws_size,
                              hipStream_t stream)
{
    const float* data    = (const float*)d_in[0];
    const float* weights = (const float*)d_in[1];
    const float* means   = (const float*)d_in[2];
    const float* cov     = (const float*)d_in[3];

    const int N = in_sizes[0] / NF;

    char* ws = (char*)d_ws;
    __hip_bfloat16* g = (__hip_bfloat16*)ws;                    // 131072 B (swizzled)
    float* t          = (float*)(ws + 131072);                  // 4096 B
    float* Cc         = (float*)(ws + 131072 + 4096);           // 64 B
    float* partials   = (float*)(ws + 131072 + 4096 + 64);      // totalWaves * 4 B

    const int nTiles     = (N + TPW * 16 - 1) / (TPW * 16);
    const int totalWaves = MAIN_BLOCKS * MAIN_WAVES;

    gmm_precompute<<<NC / 4, 256, 0, stream>>>(cov, means, weights, g, t, Cc);
    gmm_main<<<MAIN_BLOCKS, 64 * MAIN_WAVES, 0, stream>>>(
        data, (const char*)g, t, Cc, partials, nTiles, N, totalWaves);
    gmm_reduce<<<1, 256, 0, stream>>>(partials, totalWaves, (float*)d_out);
}